// Round 7
// baseline (604.762 us; speedup 1.0000x reference)
//
#include <hip/hip_runtime.h>
#include <hip/hip_bf16.h>

// OldODEFunc: B=8192, S=268, H=1024, R=8, A=256, E=4, Z=8, P=4.
// R7: 128x128 tile, BK=64 DOUBLE-BUFFERED LDS (64 KB -> 2 blocks/CU),
// 4 waves, wave-tile 64x64 (acc[4][4], m97 layout). stage(p+1) issued
// BEFORE compute(p): the barrier's vmcnt(0) drains loads that had the whole
// compute phase to land -> staging latency hidden. Grid (m=64, n=8): XCD
// affinity keeps A-slice + W L2-resident (~4 MB/XCD working set).

typedef unsigned short u16;
typedef __bf16 bf16x8 __attribute__((ext_vector_type(8)));
typedef float f32x4 __attribute__((ext_vector_type(4)));

__device__ __forceinline__ u16 f2b(float f) {
  union { float f; unsigned u; } v; v.f = f;
  unsigned r = v.u + 0x7FFFu + ((v.u >> 16) & 1u);   // RNE
  return (u16)(r >> 16);
}
__device__ __forceinline__ float b2f(u16 s) {
  union { unsigned u; float f; } v; v.u = ((unsigned)s) << 16;
  return v.f;
}

// async global->LDS, 16B per lane; lds dest = wave-uniform base + lane*16
__device__ __forceinline__ void g2l16(const u16* g, u16* l) {
  __builtin_amdgcn_global_load_lds(
      (__attribute__((address_space(1))) void*)g,
      (__attribute__((address_space(3))) void*)l, 16, 0, 0);
}

// ---------------- main GEMM ----------------
// C(128M x 128N) = A(128 x KK, row-major, LDA) @ W(N x KK)^T.
// LDS: 2 buffers x (As 128x64 + Bs 128x64) bf16, rows of 8 8-elem chunks,
// chunk swizzle: logical c at phys c ^ (row & 7) (measured conflict-free).
// 4 waves 2x2, wave-tile 64x64, acc[4][4]. Phase = BK 64.
// MODE 0: relu->bf16  1: tanh->bf16  2: tanh(+resid in-place)->bf16
// MODE 3: f32 out, cols<nreal
template<int MODE, int KK, int LDA>
__global__ __launch_bounds__(256, 2)
void pgemm(const u16* __restrict__ A, const u16* __restrict__ W,
           const float* __restrict__ bias, const u16* __restrict__ resid,
           void* __restrict__ outp, int nreal, int ldo)
{
  __shared__ __align__(16) u16 As[2][128 * 64];   // 2 x 16 KB
  __shared__ __align__(16) u16 Bs[2][128 * 64];   // 2 x 16 KB
  const int tid  = threadIdx.x;
  const int wave = tid >> 6;
  const int lane = tid & 63;
  const int m0 = blockIdx.x << 7;   // grid.x = m -> XCD = m%8 (A-affinity)
  const int n0 = blockIdx.y << 7;
  const int wr = wave >> 1, wc = wave & 1;       // 2x2 waves, 64x64 each
  const int lrow = lane & 15, quad = lane >> 4;
  const int sw = lrow & 7;

  // staging: each g2l16 covers 8 rows x 64 elems (64 lanes x 8 elems).
  const int srow  = lane >> 3;                        // 0..7 row in group
  const int sperm = ((lane & 7) ^ (srow & 7)) << 3;   // swizzled elem offset

  const u16* Ag = A + (size_t)(m0 + wave * 32 + srow) * LDA + sperm;
  const u16* Bg = W + (size_t)(n0 + wave * 32 + srow) * KK + sperm;
  u16* AsW0 = &As[0][(wave * 32) * 64];
  u16* AsW1 = &As[1][(wave * 32) * 64];
  u16* BsW0 = &Bs[0][(wave * 32) * 64];
  u16* BsW1 = &Bs[1][(wave * 32) * 64];

  f32x4 acc[4][4];
#pragma unroll
  for (int i = 0; i < 4; i++)
#pragma unroll
    for (int j = 0; j < 4; j++) { f32x4 z = {0.f,0.f,0.f,0.f}; acc[i][j] = z; }

  // stage phase 0 -> buf 0
#pragma unroll
  for (int g = 0; g < 4; g++) {
    g2l16(Ag + (size_t)g * 8 * LDA, AsW0 + g * 8 * 64);
    g2l16(Bg + (size_t)g * 8 * KK,  BsW0 + g * 8 * 64);
  }
  __syncthreads();

  const int P = KK / 64;
  for (int p = 0; p < P; p++) {
    // prefetch next phase into the other buffer (async; drained by the
    // barrier at the END of this iteration, after ~full compute phase)
    if (p + 1 < P) {
      const int ko = (p + 1) << 6;
      u16* aD = ((p + 1) & 1) ? AsW1 : AsW0;
      u16* bD = ((p + 1) & 1) ? BsW1 : BsW0;
#pragma unroll
      for (int g = 0; g < 4; g++) {
        g2l16(Ag + (size_t)g * 8 * LDA + ko, aD + g * 8 * 64);
        g2l16(Bg + (size_t)g * 8 * KK  + ko, bD + g * 8 * 64);
      }
    }
    const u16* aS = (p & 1) ? &As[1][0] : &As[0][0];
    const u16* bS = (p & 1) ? &Bs[1][0] : &Bs[0][0];
#pragma unroll
    for (int s = 0; s < 2; s++) {
      const int phys = (s * 4 + quad) ^ sw;
      bf16x8 af[4], bfr[4];
#pragma unroll
      for (int i = 0; i < 4; i++)
        af[i] = *(const bf16x8*)&aS[(wr * 64 + i * 16 + lrow) * 64 + phys * 8];
#pragma unroll
      for (int j = 0; j < 4; j++)
        bfr[j] = *(const bf16x8*)&bS[(wc * 64 + j * 16 + lrow) * 64 + phys * 8];
#pragma unroll
      for (int i = 0; i < 4; i++)
#pragma unroll
        for (int j = 0; j < 4; j++)
          acc[i][j] = __builtin_amdgcn_mfma_f32_16x16x32_bf16(af[i], bfr[j], acc[i][j], 0, 0, 0);
    }
    __syncthreads();   // drains prefetch vmcnt + guards buffer reuse
  }

  auto th = [](float x) {
    x = fminf(fmaxf(x, -40.f), 40.f);
    float a = __builtin_amdgcn_exp2f(2.88539008177793f * x);
    return (a - 1.f) * __builtin_amdgcn_rcpf(a + 1.f);
  };

  // epilogue: C/D layout col = lane&15, row = quad*4 + reg
#pragma unroll
  for (int i = 0; i < 4; i++) {
    const int rowb = m0 + wr * 64 + i * 16 + quad * 4;
#pragma unroll
    for (int j = 0; j < 4; j++) {
      const int col = n0 + wc * 64 + j * 16 + lrow;
      const float bi = (col < nreal) ? bias[col] : 0.f;
#pragma unroll
      for (int r = 0; r < 4; r++) {
        const int row = rowb + r;
        float v = acc[i][j][r] + bi;
        if (MODE == 0) {
          v = v > 0.f ? v : 0.f;
          ((u16*)outp)[(size_t)row * ldo + col] = f2b(v);
        } else if (MODE == 1) {
          ((u16*)outp)[(size_t)row * ldo + col] = f2b(th(v));
        } else if (MODE == 2) {
          v += b2f(resid[(size_t)row * ldo + col]);
          ((u16*)outp)[(size_t)row * ldo + col] = f2b(th(v));
        } else if (MODE == 3) {
          if (col < nreal) ((float*)outp)[(size_t)row * ldo + col] = v;
        }
      }
    }
  }
}

// ---------------- small GEMM for ta path ----------------
// 64M x 128N tile, BK=64, LDS-staged, xor swizzle, plain bf16 out.
__global__ __launch_bounds__(256, 4)
void gemm_bt(const u16* __restrict__ A, const u16* __restrict__ B,
             const float* __restrict__ bias, u16* __restrict__ outp,
             int K, int lda, int ldo)
{
  __shared__ __align__(16) u16 As[64 * 64];
  __shared__ __align__(16) u16 Bs[128 * 64];
  const int tid  = threadIdx.x;
  const int wave = tid >> 6;
  const int lane = tid & 63;
  const int m0 = blockIdx.y << 6;
  const int n0 = blockIdx.x << 7;
  const int wr = wave >> 1, wc = wave & 1;
  const int lrow = lane & 15, quad = lane >> 4;
  const int srow  = lane >> 3;
  const int sperm = ((lane & 7) ^ (srow & 7)) << 3;

  const u16* Ag0 = A + (size_t)(m0 + wave * 16 +  0 + srow) * lda + sperm;
  const u16* Ag1 = A + (size_t)(m0 + wave * 16 +  8 + srow) * lda + sperm;
  const u16* Bg0 = B + (size_t)(n0 + wave * 32 +  0 + srow) * K + sperm;
  const u16* Bg1 = B + (size_t)(n0 + wave * 32 +  8 + srow) * K + sperm;
  const u16* Bg2 = B + (size_t)(n0 + wave * 32 + 16 + srow) * K + sperm;
  const u16* Bg3 = B + (size_t)(n0 + wave * 32 + 24 + srow) * K + sperm;
  u16* Al0 = &As[(wave * 16 +  0) * 64];
  u16* Al1 = &As[(wave * 16 +  8) * 64];
  u16* Bl0 = &Bs[(wave * 32 +  0) * 64];
  u16* Bl1 = &Bs[(wave * 32 +  8) * 64];
  u16* Bl2 = &Bs[(wave * 32 + 16) * 64];
  u16* Bl3 = &Bs[(wave * 32 + 24) * 64];

  f32x4 acc[2][4];
#pragma unroll
  for (int i = 0; i < 2; i++)
#pragma unroll
    for (int j = 0; j < 4; j++) { f32x4 z = {0.f,0.f,0.f,0.f}; acc[i][j] = z; }

  const int swz = lrow & 7;

  for (int k0 = 0; k0 < K; k0 += 64) {
    if (k0) __syncthreads();
    g2l16(Ag0 + k0, Al0);
    g2l16(Ag1 + k0, Al1);
    g2l16(Bg0 + k0, Bl0);
    g2l16(Bg1 + k0, Bl1);
    g2l16(Bg2 + k0, Bl2);
    g2l16(Bg3 + k0, Bl3);
    __syncthreads();
#pragma unroll
    for (int s = 0; s < 2; s++) {
      const int c = (s * 4 + quad) ^ swz;
      bf16x8 af[2], bfr[4];
#pragma unroll
      for (int i = 0; i < 2; i++)
        af[i] = *(const bf16x8*)&As[(wr * 32 + i * 16 + lrow) * 64 + c * 8];
#pragma unroll
      for (int j = 0; j < 4; j++)
        bfr[j] = *(const bf16x8*)&Bs[(wc * 64 + j * 16 + lrow) * 64 + c * 8];
#pragma unroll
      for (int i = 0; i < 2; i++)
#pragma unroll
        for (int j = 0; j < 4; j++)
          acc[i][j] = __builtin_amdgcn_mfma_f32_16x16x32_bf16(af[i], bfr[j], acc[i][j], 0, 0, 0);
    }
  }

#pragma unroll
  for (int i = 0; i < 2; i++) {
    const int rowb = m0 + wr * 32 + i * 16 + quad * 4;
#pragma unroll
    for (int j = 0; j < 4; j++) {
      const int col = n0 + wc * 64 + j * 16 + lrow;
      const float bi = bias[col];
#pragma unroll
      for (int r = 0; r < 4; r++)
        outp[(size_t)(rowb + r) * ldo + col] = f2b(acc[i][j][r] + bi);
    }
  }
}

// ---------------- prep ----------------
__global__ void conv_bulk(const float* __restrict__ w1, const float* __restrict__ w2,
                          u16* __restrict__ o1, u16* __restrict__ o2)
{
  const int n4 = (8 * 1024 * 1024) / 4;
  int i = blockIdx.x * 256 + threadIdx.x;
  const float* src; u16* dst;
  if (i < n4) { src = w1; dst = o1; }
  else        { i -= n4; if (i >= n4) return; src = w2; dst = o2; }
  float4 v = ((const float4*)src)[i];
  unsigned p0 = (unsigned)f2b(v.x) | ((unsigned)f2b(v.y) << 16);
  unsigned p1 = (unsigned)f2b(v.z) | ((unsigned)f2b(v.w) << 16);
  uint2 pk; pk.x = p0; pk.y = p1;
  ((uint2*)dst)[i] = pk;
}

// W0 pad(1024x384), Wf pad(384x1024), taA(256x256), taB(256x256), x_bf(8192x384)
__global__ void conv_misc(const float* __restrict__ W0, const float* __restrict__ Wf,
                          const float* __restrict__ ta_in_w, const float* __restrict__ ta_out_w,
                          const float* __restrict__ state, const float* __restrict__ t,
                          u16* __restrict__ w0_bf, u16* __restrict__ wf_bf,
                          u16* __restrict__ taA, u16* __restrict__ taB,
                          u16* __restrict__ x_bf)
{
  int i = blockIdx.x * 256 + threadIdx.x;
  const int nW0 = 1024 * 384;
  const int nWf = 384 * 1024;
  const int nTa = 256 * 256;
  const int nX  = 8192 * 384;
  if (i < nW0) {
    int o = i / 384, k = i - o * 384;
    w0_bf[i] = (k < 270) ? f2b(W0[o * 270 + k]) : (u16)0;
    return;
  }
  i -= nW0;
  if (i < nWf) {
    int n = i >> 10;
    wf_bf[i] = (n < 268) ? f2b(Wf[i]) : (u16)0;
    return;
  }
  i -= nWf;
  if (i < nTa) { taA[i] = f2b(ta_in_w[512 * 256 + i]); return; }
  i -= nTa;
  if (i < nTa) { taB[i] = f2b(ta_out_w[i]); return; }
  i -= nTa;
  if (i < nX) {
    int r = i / 384, c = i - r * 384;
    u16 v;
    if (c < 268) v = f2b(state[r * 268 + c]);
    else if (c == 268) { float ang = t[0] * 0.2617993877991494f; v = f2b(sinf(ang)); }
    else if (c == 269) { float ang = t[0] * 0.2617993877991494f; v = f2b(cosf(ang)); }
    else v = 0;
    x_bf[i] = v;
  }
}

// out += 0.1*delta
__global__ void add_delta(float* __restrict__ out, const u16* __restrict__ eh,
                          const float* __restrict__ state,
                          const float* __restrict__ lp_in_w, const float* __restrict__ lp_in_b,
                          const float* __restrict__ lp_out_w, const float* __restrict__ lp_out_b,
                          const float* __restrict__ loc_proj_w, const float* __restrict__ loc_proj_b,
                          const float* __restrict__ loc_back_w, const float* __restrict__ loc_back_b)
{
  const int idx = blockIdx.x * 256 + threadIdx.x;
  if (idx >= 8192 * 268) return;
  const int row = idx / 268;
  const int col = idx - row * 268;
  if (col < 256) {
    out[idx] += 0.1f * (b2f(eh[row * 256 + col]) - state[idx]);
  } else if (col < 264) {
    const float* srow = state + row * 268 + 256;
    float locp[4], vv[4], dd[4];
#pragma unroll
    for (int e = 0; e < 4; e++) {
      float s = loc_proj_b[e];
#pragma unroll
      for (int z = 0; z < 8; z++) s += loc_proj_w[e * 8 + z] * srow[z];
      locp[e] = s;
    }
#pragma unroll
    for (int e = 0; e < 4; e++) {
      float s = lp_in_b[8 + e];
#pragma unroll
      for (int j = 0; j < 4; j++) s += lp_in_w[(8 + e) * 4 + j] * locp[j];
      vv[e] = s;
    }
#pragma unroll
    for (int e = 0; e < 4; e++) {
      float s = lp_out_b[e];
#pragma unroll
      for (int j = 0; j < 4; j++) s += lp_out_w[e * 4 + j] * vv[j];
      dd[e] = s - locp[e];
    }
    const int z = col - 256;
    float s = loc_back_b[z];
#pragma unroll
    for (int e = 0; e < 4; e++) s += loc_back_w[z * 4 + e] * dd[e];
    out[idx] += 0.1f * s;
  }
}

extern "C" void kernel_launch(void* const* d_in, const int* in_sizes, int n_in,
                              void* d_out, int out_size, void* d_ws, size_t ws_size,
                              hipStream_t stream)
{
  const float* t          = (const float*)d_in[0];
  const float* state      = (const float*)d_in[1];
  const float* W0         = (const float*)d_in[2];
  const float* b0         = (const float*)d_in[3];
  const float* rW1        = (const float*)d_in[4];
  const float* rb1        = (const float*)d_in[5];
  const float* rW2        = (const float*)d_in[6];
  const float* rb2        = (const float*)d_in[7];
  const float* Wf         = (const float*)d_in[8];
  const float* bfv        = (const float*)d_in[9];
  const float* lp_in_w    = (const float*)d_in[10];
  const float* lp_in_b    = (const float*)d_in[11];
  const float* lp_out_w   = (const float*)d_in[12];
  const float* lp_out_b   = (const float*)d_in[13];
  const float* ta_in_w    = (const float*)d_in[14];
  const float* ta_in_b    = (const float*)d_in[15];
  const float* ta_out_w   = (const float*)d_in[16];
  const float* ta_out_b   = (const float*)d_in[17];
  const float* loc_proj_w = (const float*)d_in[18];
  const float* loc_proj_b = (const float*)d_in[19];
  const float* loc_back_w = (const float*)d_in[20];
  const float* loc_back_b = (const float*)d_in[21];
  float* out = (float*)d_out;

  char* ws = (char*)d_ws;
  auto alloc = [&](size_t bytes) { char* p = ws; ws += (bytes + 255) & ~(size_t)255; return p; };
  u16* rw1_bf = (u16*)alloc((size_t)8 * 1024 * 1024 * 2);
  u16* rw2_bf = (u16*)alloc((size_t)8 * 1024 * 1024 * 2);
  u16* w0_bf  = (u16*)alloc((size_t)1024 * 384 * 2);
  u16* wf_bf  = (u16*)alloc((size_t)384 * 1024 * 2);
  u16* taA_bf = (u16*)alloc((size_t)256 * 256 * 2);
  u16* taB_bf = (u16*)alloc((size_t)256 * 256 * 2);
  u16* x_bf   = (u16*)alloc((size_t)8192 * 384 * 2);
  u16* h_bf   = (u16*)alloc((size_t)8192 * 1024 * 2);
  u16* tmp_bf = (u16*)alloc((size_t)8192 * 1024 * 2);
  u16* v2_bf  = (u16*)alloc((size_t)8192 * 256 * 2);
  u16* eh_bf  = (u16*)alloc((size_t)8192 * 256 * 2);

  conv_bulk<<<16384, 256, 0, stream>>>(rW1, rW2, rw1_bf, rw2_bf);
  conv_misc<<<15872, 256, 0, stream>>>(W0, Wf, ta_in_w, ta_out_w, state, t,
                                       w0_bf, wf_bf, taA_bf, taB_bf, x_bf);

  // h = relu(x @ W0^T + b0)   K padded 270->384
  pgemm<0, 384, 384><<<dim3(64, 8), 256, 0, stream>>>(x_bf, w0_bf, b0, nullptr, h_bf, 1024, 1024);

  // 8 residual blocks
  for (int r = 0; r < 8; r++) {
    pgemm<1, 1024, 1024><<<dim3(64, 8), 256, 0, stream>>>(
        h_bf, rw1_bf + ((size_t)r << 20), rb1 + (r << 10), nullptr, tmp_bf, 1024, 1024);
    pgemm<2, 1024, 1024><<<dim3(64, 8), 256, 0, stream>>>(
        tmp_bf, rw2_bf + ((size_t)r << 20), rb2 + (r << 10), h_bf, h_bf, 1024, 1024);
  }

  // ta path: v2 = x[:, :256] @ taA^T + b ; eh = v2 @ taB^T + b
  gemm_bt<<<dim3(2, 128), 256, 0, stream>>>(x_bf, taA_bf, ta_in_b + 512, v2_bf, 256, 384, 256);
  gemm_bt<<<dim3(2, 128), 256, 0, stream>>>(v2_bf, taB_bf, ta_out_b, eh_bf, 256, 256, 256);

  // core = h @ Wf^T + bf -> f32 out (N padded 268->384)
  pgemm<3, 1024, 1024><<<dim3(64, 3), 256, 0, stream>>>(h_bf, wf_bf, bfv, nullptr, out, 268, 268);

  // out += 0.1*delta
  add_delta<<<8576, 256, 0, stream>>>(out, eh_bf, state,
                                      lp_in_w, lp_in_b, lp_out_w, lp_out_b,
                                      loc_proj_w, loc_proj_b, loc_back_w, loc_back_b);
}

// Round 8
// 579.635 us; speedup vs baseline: 1.0433x; 1.0433x over previous
//
#include <hip/hip_runtime.h>
#include <hip/hip_bf16.h>

// OldODEFunc: B=8192, S=268, H=1024, R=8, A=256, E=4, Z=8, P=4.
// R8: 256Mx128N tile (85 FLOP/staged-byte beats the 60 B/cy/CU L2 ceiling),
// BK=64 double-buffered dynamic LDS (96 KB, 1 block/CU), 8 waves (512 thr)
// 4x2, wave-tile 64x64 (min LDS re-reads). Prefetch(p+1) before compute(p):
// 1241 cy MFMA cover per phase vs ~500 cy L2 latency -> drain hidden.
// Grid (m=32, n=8): XCD = m%8 -> A-slice (2 MB) + W (2 MB) L2-resident.

typedef unsigned short u16;
typedef __bf16 bf16x8 __attribute__((ext_vector_type(8)));
typedef float f32x4 __attribute__((ext_vector_type(4)));

__device__ __forceinline__ u16 f2b(float f) {
  union { float f; unsigned u; } v; v.f = f;
  unsigned r = v.u + 0x7FFFu + ((v.u >> 16) & 1u);   // RNE
  return (u16)(r >> 16);
}
__device__ __forceinline__ float b2f(u16 s) {
  union { unsigned u; float f; } v; v.u = ((unsigned)s) << 16;
  return v.f;
}

// async global->LDS, 16B per lane; lds dest = wave-uniform base + lane*16
__device__ __forceinline__ void g2l16(const u16* g, u16* l) {
  __builtin_amdgcn_global_load_lds(
      (__attribute__((address_space(1))) void*)g,
      (__attribute__((address_space(3))) void*)l, 16, 0, 0);
}

// ---------------- main GEMM ----------------
// C(256M x 128N) = A(256 x KK, row-major, LDA) @ W(N x KK)^T.
// Dynamic LDS: As[2][256*64] + Bs[2][128*64] bf16 = 96 KB.
// Rows of 8 8-elem chunks; chunk swizzle: logical c at phys c ^ (row & 7)
// (measured conflict-free R2..R7). 8 waves 4x2, wave-tile 64x64, acc[4][4].
// MODE 0: relu->bf16  1: tanh->bf16  2: tanh(+resid in-place)->bf16
// MODE 3: f32 out, cols<nreal
template<int MODE, int KK, int LDA>
__global__ __launch_bounds__(512, 2)
void pgemm(const u16* __restrict__ A, const u16* __restrict__ W,
           const float* __restrict__ bias, const u16* __restrict__ resid,
           void* __restrict__ outp, int nreal, int ldo)
{
  extern __shared__ __align__(16) u16 sm[];
  u16* Asb = sm;                    // [2][256*64]
  u16* Bsb = sm + 2 * 256 * 64;     // [2][128*64]

  const int tid  = threadIdx.x;
  const int wave = tid >> 6;
  const int lane = tid & 63;
  const int m0 = blockIdx.x << 8;   // grid.x = m -> XCD = m%8 (A-affinity)
  const int n0 = blockIdx.y << 7;
  const int wr = wave >> 1, wc = wave & 1;       // 4x2 waves, 64x64 each
  const int lrow = lane & 15, quad = lane >> 4;
  const int sw = lrow & 7;

  // staging: each g2l16 covers 8 rows x 64 elems (64 lanes x 8 elems).
  const int srow  = lane >> 3;                        // 0..7 row in group
  const int sperm = ((lane & 7) ^ (srow & 7)) << 3;   // swizzled elem offset

  const u16* Ag = A + (size_t)(m0 + wave * 32 + srow) * LDA + sperm;
  const u16* Bg = W + (size_t)(n0 + wave * 16 + srow) * KK + sperm;

  f32x4 acc[4][4];
#pragma unroll
  for (int i = 0; i < 4; i++)
#pragma unroll
    for (int j = 0; j < 4; j++) { f32x4 z = {0.f,0.f,0.f,0.f}; acc[i][j] = z; }

  // stage phase 0 -> buf 0
#pragma unroll
  for (int g = 0; g < 4; g++)
    g2l16(Ag + (size_t)g * 8 * LDA, Asb + (wave * 32 + g * 8) * 64);
#pragma unroll
  for (int g = 0; g < 2; g++)
    g2l16(Bg + (size_t)g * 8 * KK, Bsb + (wave * 16 + g * 8) * 64);
  __syncthreads();

  const int P = KK / 64;
  for (int p = 0; p < P; p++) {
    // prefetch next phase into the other buffer; drained by the barrier at
    // the end of this iteration, after a full compute phase (~1241 cy/CU)
    if (p + 1 < P) {
      const int ko = (p + 1) << 6;
      const int bo = ((p + 1) & 1);
      u16* aD = Asb + bo * 256 * 64;
      u16* bD = Bsb + bo * 128 * 64;
#pragma unroll
      for (int g = 0; g < 4; g++)
        g2l16(Ag + (size_t)g * 8 * LDA + ko, aD + (wave * 32 + g * 8) * 64);
#pragma unroll
      for (int g = 0; g < 2; g++)
        g2l16(Bg + (size_t)g * 8 * KK + ko, bD + (wave * 16 + g * 8) * 64);
    }
    const u16* aS = Asb + (p & 1) * 256 * 64;
    const u16* bS = Bsb + (p & 1) * 128 * 64;
#pragma unroll
    for (int s = 0; s < 2; s++) {
      const int phys = (s * 4 + quad) ^ sw;
      bf16x8 af[4], bfr[4];
#pragma unroll
      for (int i = 0; i < 4; i++)
        af[i] = *(const bf16x8*)&aS[(wr * 64 + i * 16 + lrow) * 64 + phys * 8];
#pragma unroll
      for (int j = 0; j < 4; j++)
        bfr[j] = *(const bf16x8*)&bS[(wc * 64 + j * 16 + lrow) * 64 + phys * 8];
#pragma unroll
      for (int i = 0; i < 4; i++)
#pragma unroll
        for (int j = 0; j < 4; j++)
          acc[i][j] = __builtin_amdgcn_mfma_f32_16x16x32_bf16(af[i], bfr[j], acc[i][j], 0, 0, 0);
    }
    __syncthreads();   // drains prefetch vmcnt + guards buffer reuse
  }

  auto th = [](float x) {
    x = fminf(fmaxf(x, -40.f), 40.f);
    float a = __builtin_amdgcn_exp2f(2.88539008177793f * x);
    return (a - 1.f) * __builtin_amdgcn_rcpf(a + 1.f);
  };

  // epilogue: C/D layout col = lane&15, row = quad*4 + reg
#pragma unroll
  for (int i = 0; i < 4; i++) {
    const int rowb = m0 + wr * 64 + i * 16 + quad * 4;
#pragma unroll
    for (int j = 0; j < 4; j++) {
      const int col = n0 + wc * 64 + j * 16 + lrow;
      const float bi = (col < nreal) ? bias[col] : 0.f;
#pragma unroll
      for (int r = 0; r < 4; r++) {
        const int row = rowb + r;
        float v = acc[i][j][r] + bi;
        if (MODE == 0) {
          v = v > 0.f ? v : 0.f;
          ((u16*)outp)[(size_t)row * ldo + col] = f2b(v);
        } else if (MODE == 1) {
          ((u16*)outp)[(size_t)row * ldo + col] = f2b(th(v));
        } else if (MODE == 2) {
          v += b2f(resid[(size_t)row * ldo + col]);
          ((u16*)outp)[(size_t)row * ldo + col] = f2b(th(v));
        } else if (MODE == 3) {
          if (col < nreal) ((float*)outp)[(size_t)row * ldo + col] = v;
        }
      }
    }
  }
}

// ---------------- small GEMM for ta path ----------------
// 64M x 128N tile, BK=64, LDS-staged, xor swizzle, plain bf16 out.
__global__ __launch_bounds__(256, 4)
void gemm_bt(const u16* __restrict__ A, const u16* __restrict__ B,
             const float* __restrict__ bias, u16* __restrict__ outp,
             int K, int lda, int ldo)
{
  __shared__ __align__(16) u16 As[64 * 64];
  __shared__ __align__(16) u16 Bs[128 * 64];
  const int tid  = threadIdx.x;
  const int wave = tid >> 6;
  const int lane = tid & 63;
  const int m0 = blockIdx.y << 6;
  const int n0 = blockIdx.x << 7;
  const int wr = wave >> 1, wc = wave & 1;
  const int lrow = lane & 15, quad = lane >> 4;
  const int srow  = lane >> 3;
  const int sperm = ((lane & 7) ^ (srow & 7)) << 3;

  const u16* Ag0 = A + (size_t)(m0 + wave * 16 +  0 + srow) * lda + sperm;
  const u16* Ag1 = A + (size_t)(m0 + wave * 16 +  8 + srow) * lda + sperm;
  const u16* Bg0 = B + (size_t)(n0 + wave * 32 +  0 + srow) * K + sperm;
  const u16* Bg1 = B + (size_t)(n0 + wave * 32 +  8 + srow) * K + sperm;
  const u16* Bg2 = B + (size_t)(n0 + wave * 32 + 16 + srow) * K + sperm;
  const u16* Bg3 = B + (size_t)(n0 + wave * 32 + 24 + srow) * K + sperm;
  u16* Al0 = &As[(wave * 16 +  0) * 64];
  u16* Al1 = &As[(wave * 16 +  8) * 64];
  u16* Bl0 = &Bs[(wave * 32 +  0) * 64];
  u16* Bl1 = &Bs[(wave * 32 +  8) * 64];
  u16* Bl2 = &Bs[(wave * 32 + 16) * 64];
  u16* Bl3 = &Bs[(wave * 32 + 24) * 64];

  f32x4 acc[2][4];
#pragma unroll
  for (int i = 0; i < 2; i++)
#pragma unroll
    for (int j = 0; j < 4; j++) { f32x4 z = {0.f,0.f,0.f,0.f}; acc[i][j] = z; }

  const int swz = lrow & 7;

  for (int k0 = 0; k0 < K; k0 += 64) {
    if (k0) __syncthreads();
    g2l16(Ag0 + k0, Al0);
    g2l16(Ag1 + k0, Al1);
    g2l16(Bg0 + k0, Bl0);
    g2l16(Bg1 + k0, Bl1);
    g2l16(Bg2 + k0, Bl2);
    g2l16(Bg3 + k0, Bl3);
    __syncthreads();
#pragma unroll
    for (int s = 0; s < 2; s++) {
      const int c = (s * 4 + quad) ^ swz;
      bf16x8 af[2], bfr[4];
#pragma unroll
      for (int i = 0; i < 2; i++)
        af[i] = *(const bf16x8*)&As[(wr * 32 + i * 16 + lrow) * 64 + c * 8];
#pragma unroll
      for (int j = 0; j < 4; j++)
        bfr[j] = *(const bf16x8*)&Bs[(wc * 64 + j * 16 + lrow) * 64 + c * 8];
#pragma unroll
      for (int i = 0; i < 2; i++)
#pragma unroll
        for (int j = 0; j < 4; j++)
          acc[i][j] = __builtin_amdgcn_mfma_f32_16x16x32_bf16(af[i], bfr[j], acc[i][j], 0, 0, 0);
    }
  }

#pragma unroll
  for (int i = 0; i < 2; i++) {
    const int rowb = m0 + wr * 32 + i * 16 + quad * 4;
#pragma unroll
    for (int j = 0; j < 4; j++) {
      const int col = n0 + wc * 64 + j * 16 + lrow;
      const float bi = bias[col];
#pragma unroll
      for (int r = 0; r < 4; r++)
        outp[(size_t)(rowb + r) * ldo + col] = f2b(acc[i][j][r] + bi);
    }
  }
}

// ---------------- prep ----------------
__global__ void conv_bulk(const float* __restrict__ w1, const float* __restrict__ w2,
                          u16* __restrict__ o1, u16* __restrict__ o2)
{
  const int n4 = (8 * 1024 * 1024) / 4;
  int i = blockIdx.x * 256 + threadIdx.x;
  const float* src; u16* dst;
  if (i < n4) { src = w1; dst = o1; }
  else        { i -= n4; if (i >= n4) return; src = w2; dst = o2; }
  float4 v = ((const float4*)src)[i];
  unsigned p0 = (unsigned)f2b(v.x) | ((unsigned)f2b(v.y) << 16);
  unsigned p1 = (unsigned)f2b(v.z) | ((unsigned)f2b(v.w) << 16);
  uint2 pk; pk.x = p0; pk.y = p1;
  ((uint2*)dst)[i] = pk;
}

// W0 pad(1024x384), Wf pad(384x1024), taA(256x256), taB(256x256), x_bf(8192x384)
__global__ void conv_misc(const float* __restrict__ W0, const float* __restrict__ Wf,
                          const float* __restrict__ ta_in_w, const float* __restrict__ ta_out_w,
                          const float* __restrict__ state, const float* __restrict__ t,
                          u16* __restrict__ w0_bf, u16* __restrict__ wf_bf,
                          u16* __restrict__ taA, u16* __restrict__ taB,
                          u16* __restrict__ x_bf)
{
  int i = blockIdx.x * 256 + threadIdx.x;
  const int nW0 = 1024 * 384;
  const int nWf = 384 * 1024;
  const int nTa = 256 * 256;
  const int nX  = 8192 * 384;
  if (i < nW0) {
    int o = i / 384, k = i - o * 384;
    w0_bf[i] = (k < 270) ? f2b(W0[o * 270 + k]) : (u16)0;
    return;
  }
  i -= nW0;
  if (i < nWf) {
    int n = i >> 10;
    wf_bf[i] = (n < 268) ? f2b(Wf[i]) : (u16)0;
    return;
  }
  i -= nWf;
  if (i < nTa) { taA[i] = f2b(ta_in_w[512 * 256 + i]); return; }
  i -= nTa;
  if (i < nTa) { taB[i] = f2b(ta_out_w[i]); return; }
  i -= nTa;
  if (i < nX) {
    int r = i / 384, c = i - r * 384;
    u16 v;
    if (c < 268) v = f2b(state[r * 268 + c]);
    else if (c == 268) { float ang = t[0] * 0.2617993877991494f; v = f2b(sinf(ang)); }
    else if (c == 269) { float ang = t[0] * 0.2617993877991494f; v = f2b(cosf(ang)); }
    else v = 0;
    x_bf[i] = v;
  }
}

// out += 0.1*delta
__global__ void add_delta(float* __restrict__ out, const u16* __restrict__ eh,
                          const float* __restrict__ state,
                          const float* __restrict__ lp_in_w, const float* __restrict__ lp_in_b,
                          const float* __restrict__ lp_out_w, const float* __restrict__ lp_out_b,
                          const float* __restrict__ loc_proj_w, const float* __restrict__ loc_proj_b,
                          const float* __restrict__ loc_back_w, const float* __restrict__ loc_back_b)
{
  const int idx = blockIdx.x * 256 + threadIdx.x;
  if (idx >= 8192 * 268) return;
  const int row = idx / 268;
  const int col = idx - row * 268;
  if (col < 256) {
    out[idx] += 0.1f * (b2f(eh[row * 256 + col]) - state[idx]);
  } else if (col < 264) {
    const float* srow = state + row * 268 + 256;
    float locp[4], vv[4], dd[4];
#pragma unroll
    for (int e = 0; e < 4; e++) {
      float s = loc_proj_b[e];
#pragma unroll
      for (int z = 0; z < 8; z++) s += loc_proj_w[e * 8 + z] * srow[z];
      locp[e] = s;
    }
#pragma unroll
    for (int e = 0; e < 4; e++) {
      float s = lp_in_b[8 + e];
#pragma unroll
      for (int j = 0; j < 4; j++) s += lp_in_w[(8 + e) * 4 + j] * locp[j];
      vv[e] = s;
    }
#pragma unroll
    for (int e = 0; e < 4; e++) {
      float s = lp_out_b[e];
#pragma unroll
      for (int j = 0; j < 4; j++) s += lp_out_w[e * 4 + j] * vv[j];
      dd[e] = s - locp[e];
    }
    const int z = col - 256;
    float s = loc_back_b[z];
#pragma unroll
    for (int e = 0; e < 4; e++) s += loc_back_w[z * 4 + e] * dd[e];
    out[idx] += 0.1f * s;
  }
}

extern "C" void kernel_launch(void* const* d_in, const int* in_sizes, int n_in,
                              void* d_out, int out_size, void* d_ws, size_t ws_size,
                              hipStream_t stream)
{
  const float* t          = (const float*)d_in[0];
  const float* state      = (const float*)d_in[1];
  const float* W0         = (const float*)d_in[2];
  const float* b0         = (const float*)d_in[3];
  const float* rW1        = (const float*)d_in[4];
  const float* rb1        = (const float*)d_in[5];
  const float* rW2        = (const float*)d_in[6];
  const float* rb2        = (const float*)d_in[7];
  const float* Wf         = (const float*)d_in[8];
  const float* bfv        = (const float*)d_in[9];
  const float* lp_in_w    = (const float*)d_in[10];
  const float* lp_in_b    = (const float*)d_in[11];
  const float* lp_out_w   = (const float*)d_in[12];
  const float* lp_out_b   = (const float*)d_in[13];
  const float* ta_in_w    = (const float*)d_in[14];
  const float* ta_in_b    = (const float*)d_in[15];
  const float* ta_out_w   = (const float*)d_in[16];
  const float* ta_out_b   = (const float*)d_in[17];
  const float* loc_proj_w = (const float*)d_in[18];
  const float* loc_proj_b = (const float*)d_in[19];
  const float* loc_back_w = (const float*)d_in[20];
  const float* loc_back_b = (const float*)d_in[21];
  float* out = (float*)d_out;

  char* ws = (char*)d_ws;
  auto alloc = [&](size_t bytes) { char* p = ws; ws += (bytes + 255) & ~(size_t)255; return p; };
  u16* rw1_bf = (u16*)alloc((size_t)8 * 1024 * 1024 * 2);
  u16* rw2_bf = (u16*)alloc((size_t)8 * 1024 * 1024 * 2);
  u16* w0_bf  = (u16*)alloc((size_t)1024 * 384 * 2);
  u16* wf_bf  = (u16*)alloc((size_t)384 * 1024 * 2);
  u16* taA_bf = (u16*)alloc((size_t)256 * 256 * 2);
  u16* taB_bf = (u16*)alloc((size_t)256 * 256 * 2);
  u16* x_bf   = (u16*)alloc((size_t)8192 * 384 * 2);
  u16* h_bf   = (u16*)alloc((size_t)8192 * 1024 * 2);
  u16* tmp_bf = (u16*)alloc((size_t)8192 * 1024 * 2);
  u16* v2_bf  = (u16*)alloc((size_t)8192 * 256 * 2);
  u16* eh_bf  = (u16*)alloc((size_t)8192 * 256 * 2);

  const int lds = (2 * 256 * 64 + 2 * 128 * 64) * 2;   // 98304 B
  hipFuncSetAttribute(reinterpret_cast<const void*>(pgemm<0, 384, 384>),
                      hipFuncAttributeMaxDynamicSharedMemorySize, lds);
  hipFuncSetAttribute(reinterpret_cast<const void*>(pgemm<1, 1024, 1024>),
                      hipFuncAttributeMaxDynamicSharedMemorySize, lds);
  hipFuncSetAttribute(reinterpret_cast<const void*>(pgemm<2, 1024, 1024>),
                      hipFuncAttributeMaxDynamicSharedMemorySize, lds);
  hipFuncSetAttribute(reinterpret_cast<const void*>(pgemm<3, 1024, 1024>),
                      hipFuncAttributeMaxDynamicSharedMemorySize, lds);

  conv_bulk<<<16384, 256, 0, stream>>>(rW1, rW2, rw1_bf, rw2_bf);
  conv_misc<<<15872, 256, 0, stream>>>(W0, Wf, ta_in_w, ta_out_w, state, t,
                                       w0_bf, wf_bf, taA_bf, taB_bf, x_bf);

  // h = relu(x @ W0^T + b0)   K padded 270->384
  pgemm<0, 384, 384><<<dim3(32, 8), 512, lds, stream>>>(x_bf, w0_bf, b0, nullptr, h_bf, 1024, 1024);

  // 8 residual blocks
  for (int r = 0; r < 8; r++) {
    pgemm<1, 1024, 1024><<<dim3(32, 8), 512, lds, stream>>>(
        h_bf, rw1_bf + ((size_t)r << 20), rb1 + (r << 10), nullptr, tmp_bf, 1024, 1024);
    pgemm<2, 1024, 1024><<<dim3(32, 8), 512, lds, stream>>>(
        tmp_bf, rw2_bf + ((size_t)r << 20), rb2 + (r << 10), h_bf, h_bf, 1024, 1024);
  }

  // ta path: v2 = x[:, :256] @ taA^T + b ; eh = v2 @ taB^T + b
  gemm_bt<<<dim3(2, 128), 256, 0, stream>>>(x_bf, taA_bf, ta_in_b + 512, v2_bf, 256, 384, 256);
  gemm_bt<<<dim3(2, 128), 256, 0, stream>>>(v2_bf, taB_bf, ta_out_b, eh_bf, 256, 256, 256);

  // core = h @ Wf^T + bf -> f32 out (N padded 268->384)
  pgemm<3, 1024, 1024><<<dim3(32, 3), 512, lds, stream>>>(h_bf, wf_bf, bfv, nullptr, out, 268, 268);

  // out += 0.1*delta
  add_delta<<<8576, 256, 0, stream>>>(out, eh_bf, state,
                                      lp_in_w, lp_in_b, lp_out_w, lp_out_b,
                                      loc_proj_w, loc_proj_b, loc_back_w, loc_back_b);
}